// Round 11
// baseline (298.683 us; speedup 1.0000x reference)
//
#include <hip/hip_runtime.h>

typedef __attribute__((ext_vector_type(8))) __bf16 bf16x8;
typedef __attribute__((ext_vector_type(4))) float f32x4;
typedef __attribute__((ext_vector_type(4))) float f4;
typedef __attribute__((ext_vector_type(4))) unsigned short ushort4_t;

__device__ inline void gload16(const void* g, void* l) {
  __builtin_amdgcn_global_load_lds(
      (const __attribute__((address_space(1))) unsigned int*)g,
      (__attribute__((address_space(3))) unsigned int*)l, 16, 0, 0);
}

#define FENCE asm volatile("" ::: "memory")

// ---------------------------------------------------------------- prep: convert + W-transpose + bias pack + lsum zero
// One launch (6220 blocks x 256 thr), blockIdx.x-routed:
//   [0,2048)    : X fp32 -> bf16 (grid-stride, 16B/lane)
//   [2048,6144) : W[k][n] fp32 -> Wt[n][k] bf16, 4 weights (1024 blocks each)
//   [6144,6156) : bias pack 3x1024 fp32
//   [6156,6220) : zero lsum[16384] (row-sum accumulators in the Sb hole)
__global__ __launch_bounds__(256) void prep_k(
    const float* __restrict__ y,
    const float* __restrict__ Wq, const float* __restrict__ Wk,
    const float* __restrict__ Wv, const float* __restrict__ Wo,
    const float* __restrict__ bq, const float* __restrict__ bk,
    const float* __restrict__ bv,
    __bf16* __restrict__ Xb, __bf16* __restrict__ Wt, float* __restrict__ bqkv,
    char* __restrict__ sb) {
  __shared__ float tile[32][33];
  const int bid = blockIdx.x, t = threadIdx.x;
  if (bid < 2048) {
    for (int i = bid * 256 + t; i < 2097152; i += 524288) {
      f4 a = ((const f4*)y)[2 * (long long)i];
      f4 b = ((const f4*)y)[2 * (long long)i + 1];
      bf16x8 o;
#pragma unroll
      for (int e = 0; e < 4; e++) { o[e] = (__bf16)a[e]; o[e + 4] = (__bf16)b[e]; }
      ((bf16x8*)Xb)[i] = o;
    }
  } else if (bid < 6144) {
    const int idx = bid - 2048;
    const int z = idx >> 10, rem = idx & 1023;
    const int bx = rem & 31, by = rem >> 5;
    const float* W = (z == 0) ? Wq : (z == 1) ? Wk : (z == 2) ? Wv : Wo;
    __bf16* O = Wt + (long long)z * 1048576;
    const int tx = t & 31, ty = t >> 5;
    const int n0 = bx * 32, k0 = by * 32;
#pragma unroll
    for (int i = 0; i < 4; i++)
      tile[ty + i * 8][tx] = W[(long long)(k0 + ty + i * 8) * 1024 + n0 + tx];
    __syncthreads();
#pragma unroll
    for (int i = 0; i < 4; i++)
      O[(long long)(n0 + ty + i * 8) * 1024 + k0 + tx] = (__bf16)tile[tx][ty + i * 8];
  } else if (bid < 6156) {
    const int i = (bid - 6144) * 256 + t;
    if (i < 3072) {
      const float* src = (i < 1024) ? bq : (i < 2048) ? bk : bv;
      bqkv[i] = src[i & 1023];
    }
  } else {
    // lsum(gr) at sb + (gr&127)*4096 + 2048 + (gr>>7)*4  (Sb batch-0 hole:
    // rows 0..127 only use cols [0,256); elems [1024,1280) are dead)
    const int gr = (bid - 6156) * 256 + t;  // 0..16383
    *(float*)(sb + (long long)(gr & 127) * 4096 + 2048 + (gr >> 7) * 4) = 0.0f;
  }
}

// ---------------------------------------------------------------- gemm8: 256x256 tile, BK=64, 8-phase
// (round-4 form; retained for reference/unused shapes).
#define LOADA(BASE, MIB)                                                       \
  _Pragma("unroll") for (int mi = 0; mi < 4; mi++)                             \
      _Pragma("unroll") for (int kh = 0; kh < 2; kh++) {                       \
    int row = ((MIB) + mi) * 16 + ln15;                                        \
    int pb = (row * 128 + (kh * 32 + kq * 8) * 2) ^ ((row & 7) << 4);          \
    a[mi][kh] = *(const bf16x8*)((BASE) + pb);                                 \
  }

#define LOADB(BASE, NIB)                                                       \
  _Pragma("unroll") for (int ni = 0; ni < 2; ni++)                             \
      _Pragma("unroll") for (int kh = 0; kh < 2; kh++) {                       \
    int row = brow0 + ((NIB) + ni) * 16 + ln15;                                \
    int pb = (row * 128 + (kh * 32 + kq * 8) * 2) ^ ((row & 7) << 4);          \
    b[(NIB) + ni][kh] = *(const bf16x8*)((BASE) + pb);                         \
  }

#define MFMAQ(MI0, NI0)                                                        \
  _Pragma("unroll") for (int mi = 0; mi < 4; mi++)                             \
      _Pragma("unroll") for (int ni = 0; ni < 2; ni++)                         \
          _Pragma("unroll") for (int kh = 0; kh < 2; kh++)                     \
              acc[(MI0) + mi][(NI0) + ni] =                                    \
      __builtin_amdgcn_mfma_f32_16x16x32_bf16(a[mi][kh], b[(NI0) + ni][kh],    \
                                              acc[(MI0) + mi][(NI0) + ni], 0, 0, 0);

#define BARW                                           \
  FENCE;                                               \
  __builtin_amdgcn_s_barrier();                        \
  FENCE;                                               \
  __builtin_amdgcn_s_setprio(1);

#define ENDP                                           \
  __builtin_amdgcn_s_setprio(0);                       \
  FENCE;                                               \
  __builtin_amdgcn_s_barrier();                        \
  FENCE;

#define ENDPB                                          \
  __builtin_amdgcn_s_setprio(0);                       \
  asm volatile("s_waitcnt vmcnt(8)" ::: "memory");     \
  __builtin_amdgcn_s_barrier();                        \
  FENCE;

// ---------------------------------------------------------------- gemm2w: 128x256 tile, BK=32, 2 wgs/CU
// 8 waves (2M x 4N), per-wave 64x64 (acc[4][4]; ~60 VGPR -> 4 waves/SIMD).
// LDS 72 KiB: A triple-buffered (3 x 8 KiB) + B triple-buffered (3 x 16 KiB).
// Swizzle ^(((row>>1)&3)<<4): free 2-way bank aliasing (262K conflicts, R8).
// 2-deep prefetch, vmcnt(3) at tile end. 2 wgs/CU hides barrier/vmcnt stalls.
// OUT: 0 = bf16 C; 1 = f32 C;
//      2 = fused QKV z-routing (z<2 scalar bf16 C, z==2 V->vt_out[b][d][t]);
//      3 = S epilogue: causal mask + exp (no max-sub: |s|<~3 bounded), write
//          bf16 P, per-row sums atomicAdd into lsum (vt_out = Sb base);
//      4 = PV epilogue: scale by 1/lsum[row] (bias0 = lsum base as float*).
// SWZ: 0 = A-stripe (XCD q owns br in [16q,16q+16), br fastest; needs nbx=128)
//      4 = PV complementary-pair: 512 wgs; per-CU slot sum == 68 (exact).
//      5 = S-gemm causal: 576 wgs; z = XCD = batch; row-pair enumeration.
template <int OUT, int SWZ>
__global__ __launch_bounds__(512, 4) void gemm2w(
    const __bf16* __restrict__ A0, int lda, long long sAz,
    const __bf16* __restrict__ B0, int ldb, long long sBz,
    void* __restrict__ C0v, int ldc, long long sCz,
    const float* __restrict__ bias0, int sBiasZ,
    float scale_z0, int k_tiles_base, int k_tiles_per_br,
    __bf16* __restrict__ vt_out) {
  int br, bc, z;
  {
    const int lin = (blockIdx.z * gridDim.y + blockIdx.y) * gridDim.x + blockIdx.x;
    if (SWZ == 4) {
      // complementary-pair causal schedule (gridDim = 512,1,1)
      z = lin & 7;
      const int r = (lin >> 3) & 7;
      bc = (lin >> 6) & 3;
      const int half = lin >> 8;  // 0: long half (br 8..15), 1: short (7..0)
      br = half ? (7 - r) : (8 + r);
    } else if (SWZ == 5) {
      // packed causal 128x256 tiles (gridDim = 576,1,1)
      z = lin & 7;
      const int c = lin >> 3;  // 0..71
      int m = (int)((sqrtf((float)(4 * c + 1)) - 1.0f) * 0.5f);
      if (c < m * (m + 1)) m--;
      if (c >= (m + 1) * (m + 2)) m++;
      const int r = c - m * (m + 1);  // 0..2m+1
      if (r >= m + 1) { br = 2 * m + 1; bc = r - (m + 1); }
      else { br = 2 * m; bc = r; }
    } else {
      const int q = lin & 7, c = lin >> 3;
      br = q * 16 + (c & 15);
      const int rest = c >> 4;
      const int nby = gridDim.y;
      bc = rest % nby;
      z = rest / nby;
    }
  }
  const int kt = k_tiles_base + k_tiles_per_br * br;  // >= 2 (BK=32 units)

  // 72 KiB LDS: A bufs at 0,4096,8192 (elems); B bufs at 12288,20480,28672
  __shared__ __align__(16) __bf16 lds[36864];

  const int t = threadIdx.x, w = t >> 6, lane = t & 63;
  const int wm = w >> 2, wn = w & 3;
  const int ln15 = lane & 15, kq = lane >> 4;

  const __bf16* A = A0 + (long long)z * sAz + (long long)br * 128 * lda;
  const __bf16* B = B0 + (long long)z * sBz + (long long)bc * 256 * ldb;

  // staging src (dest linear o = t*16 bytes, inverse-swizzled; 64B rows;
  // swz touches bits 4-5, row = o>>6 unchanged -> lo = o ^ (((o>>7)&3)<<4))
  const __bf16* sA;
  const __bf16* sB[2];
  {
    int o = t * 16;
    int lo = o ^ (((o >> 7) & 3) << 4);
    sA = A + (long long)(lo >> 6) * lda + ((lo & 63) >> 1);
  }
#pragma unroll
  for (int i = 0; i < 2; i++) {
    int o = i * 8192 + t * 16;
    int lo = o ^ (((o >> 7) & 3) << 4);
    sB[i] = B + (long long)(lo >> 6) * ldb + ((lo & 63) >> 1);
  }

  auto stgA = [&](int buf, int g) {
    int kc = g < kt ? g : kt - 1;
    gload16(sA + kc * 32, lds + buf * 4096 + w * 512);
  };
  auto stgB = [&](int buf, int g) {
    int kc = g < kt ? g : kt - 1;
#pragma unroll
    for (int i = 0; i < 2; i++)
      gload16(sB[i] + kc * 32, lds + 12288 + buf * 8192 + i * 4096 + w * 512);
  };

  f32x4 acc[4][4] = {};
  bf16x8 a[4], b[4];

  // prologue: tiles 0 and 1 (3 loads each); vmcnt(3) -> tile 0 resident
  stgA(0, 0); stgB(0, 0);
  stgA(1, 1); stgB(1, 1);
  asm volatile("s_waitcnt vmcnt(3)" ::: "memory");
  __builtin_amdgcn_s_barrier();
  FENCE;

  int cb = 0, db = 2;
  for (int kk = 0; kk < kt; kk++) {
    const char* Ab = (const char*)(lds + cb * 4096);
    const char* Bb = (const char*)(lds + 12288 + cb * 8192);
#pragma unroll
    for (int mi = 0; mi < 4; mi++) {
      int row = wm * 64 + mi * 16 + ln15;
      int pb = (row * 64 + kq * 16) ^ (((row >> 1) & 3) << 4);
      a[mi] = *(const bf16x8*)(Ab + pb);
    }
#pragma unroll
    for (int ni = 0; ni < 4; ni++) {
      int row = wn * 64 + ni * 16 + ln15;
      int pb = (row * 64 + kq * 16) ^ (((row >> 1) & 3) << 4);
      b[ni] = *(const bf16x8*)(Bb + pb);
    }
    stgA(db, kk + 2);
    stgB(db, kk + 2);
    FENCE;
    __builtin_amdgcn_s_barrier();
    FENCE;
    __builtin_amdgcn_s_setprio(1);
#pragma unroll
    for (int mi = 0; mi < 4; mi++)
#pragma unroll
      for (int ni = 0; ni < 4; ni++)
        acc[mi][ni] = __builtin_amdgcn_mfma_f32_16x16x32_bf16(
            a[mi], b[ni], acc[mi][ni], 0, 0, 0);
    __builtin_amdgcn_s_setprio(0);
    asm volatile("s_waitcnt vmcnt(3)" ::: "memory");
    __builtin_amdgcn_s_barrier();
    FENCE;
    cb = (cb == 2) ? 0 : cb + 1;
    db = (db == 2) ? 0 : db + 1;
  }
  // drain clamped-dup prefetches before LDS reuse / exit (stale DMA safety)
  asm volatile("s_waitcnt vmcnt(0)" ::: "memory");

  if (OUT == 2 && z == 2) {
    // V: stage 128(t) x 256(d) tile into LDS as [d][t] (256B rows, XOR
    // ((d&7)<<4) -> 2-way), then coalesced 16B stores into vt_out[b][d][t].
    __syncthreads();
    char* lb = (char*)lds;
#pragma unroll
    for (int mi = 0; mi < 4; mi++) {
#pragma unroll
      for (int ni = 0; ni < 4; ni++) {
        const int d = wn * 64 + ni * 16 + ln15;
        const int tl = wm * 64 + kq * 4 + mi * 16;
        const float bb = bias0[2048 + bc * 256 + d];
        ushort4_t p;
#pragma unroll
        for (int j = 0; j < 4; j++) {
          union { __bf16 h; unsigned short u; } cv;
          cv.h = (__bf16)(acc[mi][ni][j] + bb);
          p[j] = cv.u;
        }
        int byte = (d * 256 + tl * 2) ^ ((d & 7) << 4);
        *(ushort4_t*)(lb + byte) = p;
      }
    }
    __syncthreads();
    const int bz = br >> 4;
    const int t0 = (br & 15) * 128;
    __bf16* vbase = vt_out + (long long)bz * 2097152 +
                    (long long)(bc * 256) * 2048 + t0;
#pragma unroll
    for (int it = 0; it < 8; it++) {
      int idx = it * 512 + t;  // 16B units, 4096 total (256 d x 16)
      int d = idx >> 4, tc = idx & 15;
      int byte = (d * 256 + tc * 16) ^ ((d & 7) << 4);
      bf16x8 vv = *(const bf16x8*)(lb + byte);
      *(bf16x8*)(vbase + (long long)d * 2048 + tc * 8) = vv;
    }
  } else if (OUT == 3) {
    // S epilogue: causal mask + exp, write bf16 P, accumulate row sums.
    // lsum(gr) lives in the Sb batch-0 hole (see prep_k); vt_out = Sb base.
    char* lsb = (char*)vt_out;
    const int row0 = br * 128 + wm * 64 + kq * 4;
    const int col0 = bc * 256 + wn * 64 + ln15;
#pragma unroll
    for (int mi = 0; mi < 4; mi++) {
#pragma unroll
      for (int j = 0; j < 4; j++) {
        const int rr = row0 + mi * 16 + j;
        float psum = 0.0f;
#pragma unroll
        for (int ni = 0; ni < 4; ni++) {
          const int cc = col0 + ni * 16;
          float p = (cc <= rr) ? __expf(acc[mi][ni][j]) : 0.0f;
          __bf16 pb = (__bf16)p;
          ((__bf16*)C0v)[(long long)z * sCz + (long long)rr * ldc + cc] = pb;
          psum += (float)pb;  // sum the bf16-rounded values PV will consume
        }
        // reduce across the 16-lane col group (ln15 bits only)
#pragma unroll
        for (int o = 8; o >= 1; o >>= 1) psum += __shfl_xor(psum, o);
        if (ln15 == 0) {
          const int gr = z * 2048 + rr;
          atomicAdd((float*)(lsb + (long long)(gr & 127) * 4096 + 2048 +
                             (gr >> 7) * 4),
                    psum);
        }
      }
    }
  } else if (OUT == 4) {
    // PV epilogue: normalize by 1/lsum[row]; bias0 = lsum base (float*)
    const int row0 = br * 128 + wm * 64 + kq * 4;
    const int col0 = bc * 256 + wn * 64 + ln15;
#pragma unroll
    for (int mi = 0; mi < 4; mi++) {
#pragma unroll
      for (int j = 0; j < 4; j++) {
        const int rr = row0 + mi * 16 + j;
        const int gr = z * 2048 + rr;
        const float rl = 1.0f / bias0[(gr & 127) * 1024 + 512 + (gr >> 7)];
#pragma unroll
        for (int ni = 0; ni < 4; ni++) {
          const int cc = col0 + ni * 16;
          ((__bf16*)C0v)[(long long)z * sCz + (long long)rr * ldc + cc] =
              (__bf16)(acc[mi][ni][j] * rl);
        }
      }
    }
  } else {
    const int row0 = br * 128 + wm * 64 + kq * 4;
    const int col0 = bc * 256 + wn * 64 + ln15;
    const float scale = (z == 0) ? scale_z0 : 1.0f;
    const float* bias = bias0 ? (bias0 + (long long)z * sBiasZ) : nullptr;
#pragma unroll
    for (int mi = 0; mi < 4; mi++) {
#pragma unroll
      for (int ni = 0; ni < 4; ni++) {
        const int rr = row0 + mi * 16;
        const int cc = col0 + ni * 16;
        const float bb = bias ? bias[cc] : 0.0f;
#pragma unroll
        for (int j = 0; j < 4; j++) {
          float v = (acc[mi][ni][j] + bb) * scale;
          long long off = (long long)z * sCz + (long long)(rr + j) * ldc + cc;
          if (OUT == 1)
            ((float*)C0v)[off] = v;
          else
            ((__bf16*)C0v)[off] = (__bf16)v;
        }
      }
    }
  }
}

// ---------------------------------------------------------------- launch
extern "C" void kernel_launch(void* const* d_in, const int* in_sizes, int n_in,
                              void* d_out, int out_size, void* d_ws, size_t ws_size,
                              hipStream_t stream) {
  const float* y  = (const float*)d_in[0];
  const float* Wq = (const float*)d_in[1];
  const float* bq = (const float*)d_in[2];
  const float* Wk = (const float*)d_in[3];
  const float* bk = (const float*)d_in[4];
  const float* Wv = (const float*)d_in[5];
  const float* bv = (const float*)d_in[6];
  const float* Wo = (const float*)d_in[7];
  const float* bo = (const float*)d_in[8];

  char* ws = (char*)d_ws;
  __bf16* Xb   = (__bf16*)(ws + 0);            // 16384x1024 bf16 X   (32 MiB) [ctx after PV]
  __bf16* Wt   = (__bf16*)(ws + 33554432);     // 4 x [1024][1024] bf16 W^T (8 MiB)
  float*  bqkv = (float*)(ws + 41943040);      // 3x1024 fp32
  __bf16* Qb   = (__bf16*)(ws + 41955328);     // 8x2048x1024 Q       (32 MiB)
  __bf16* Kb   = (__bf16*)(ws + 75509760);     // 8x2048x1024 K       (32 MiB)
  __bf16* Vt   = (__bf16*)(ws + 109064192);    // 8 x [1024][2048] V^T (32 MiB)
  __bf16* Sb   = (__bf16*)(ws + 142618624);    // 8x2048x2048 S/P (ends at 209,727,488)
  __bf16* ctx  = (__bf16*)(ws + 0);            // PV output reuses Xb region

  if (ws_size < 209727488u) return;

  // fused prep: X->bf16, W transposes, bias pack, lsum zero (one launch)
  prep_k<<<6220, 256, 0, stream>>>(y, Wq, Wk, Wv, Wo, bq, bk, bv, Xb, Wt, bqkv,
                                   (char*)Sb);

  // Fused QKV projection: 128x256-tile 2-wg/CU kernel (conflict-free swizzle),
  // z-split (z0->Qb scaled, z1->Kb, z2->Vt via LDS transpose). A-stripe, z slowest.
  gemm2w<2, 0><<<dim3(128, 4, 3), 512, 0, stream>>>(
      Xb, 1024, 0LL, Wt, 1024, 1048576LL,
      Qb, 1024, 16777216LL, bqkv, 1024, 0.03125f, 32, 0, Vt);

  // S = Q @ K^T with fused exp+mask+rowsum epilogue (no separate softmax):
  // 128x256 causal tiles, 576 wgs at 2/CU, z = XCD = batch.
  gemm2w<3, 5><<<dim3(576, 1, 1), 512, 0, stream>>>(
      Qb, 1024, 2097152LL, Kb, 1024, 2097152LL,
      Sb, 2048, 4194304LL, nullptr, 0, 1.0f, 32, 0, Sb);

  // ctx = P @ V with 1/lsum normalization epilogue: complementary-pair
  // schedule (512 wgs, per-CU slot sum == 68, 2 wgs/CU).
  gemm2w<4, 4><<<dim3(512, 1, 1), 512, 0, stream>>>(
      Sb, 2048, 4194304LL, Vt, 2048, 2097152LL,
      ctx, 1024, 2097152LL, (const float*)Sb, 0, 1.0f, 4, 4, nullptr);

  // out = ctx @ Wo + bo (fp32 epilogue to d_out), gemm2w A-stripe, 2 wgs/CU
  gemm2w<1, 0><<<dim3(128, 4, 1), 512, 0, stream>>>(
      ctx, 1024, 0LL, Wt + 3 * 1048576, 1024, 0LL,
      d_out, 1024, 0LL, bo, 0, 1.0f, 32, 0, nullptr);
}

// Round 12
// 298.209 us; speedup vs baseline: 1.0016x; 1.0016x over previous
//
#include <hip/hip_runtime.h>

typedef __attribute__((ext_vector_type(8))) __bf16 bf16x8;
typedef __attribute__((ext_vector_type(4))) float f32x4;
typedef __attribute__((ext_vector_type(4))) float f4;
typedef __attribute__((ext_vector_type(4))) unsigned short ushort4_t;

__device__ inline void gload16(const void* g, void* l) {
  __builtin_amdgcn_global_load_lds(
      (const __attribute__((address_space(1))) unsigned int*)g,
      (__attribute__((address_space(3))) unsigned int*)l, 16, 0, 0);
}

#define FENCE asm volatile("" ::: "memory")

// ---------------------------------------------------------------- prep: convert + W-transpose + bias pack + lsum zero
// One launch (6220 blocks x 256 thr), blockIdx.x-routed:
//   [0,2048)    : X fp32 -> bf16 (grid-stride, 16B/lane)
//   [2048,6144) : W[k][n] fp32 -> Wt[n][k] bf16, 4 weights (1024 blocks each)
//   [6144,6156) : bias pack 3x1024 fp32
//   [6156,6220) : zero lsum[16384] (row-sum accumulators in the Sb hole)
__global__ __launch_bounds__(256) void prep_k(
    const float* __restrict__ y,
    const float* __restrict__ Wq, const float* __restrict__ Wk,
    const float* __restrict__ Wv, const float* __restrict__ Wo,
    const float* __restrict__ bq, const float* __restrict__ bk,
    const float* __restrict__ bv,
    __bf16* __restrict__ Xb, __bf16* __restrict__ Wt, float* __restrict__ bqkv,
    char* __restrict__ sb) {
  __shared__ float tile[32][33];
  const int bid = blockIdx.x, t = threadIdx.x;
  if (bid < 2048) {
    for (int i = bid * 256 + t; i < 2097152; i += 524288) {
      f4 a = ((const f4*)y)[2 * (long long)i];
      f4 b = ((const f4*)y)[2 * (long long)i + 1];
      bf16x8 o;
#pragma unroll
      for (int e = 0; e < 4; e++) { o[e] = (__bf16)a[e]; o[e + 4] = (__bf16)b[e]; }
      ((bf16x8*)Xb)[i] = o;
    }
  } else if (bid < 6144) {
    const int idx = bid - 2048;
    const int z = idx >> 10, rem = idx & 1023;
    const int bx = rem & 31, by = rem >> 5;
    const float* W = (z == 0) ? Wq : (z == 1) ? Wk : (z == 2) ? Wv : Wo;
    __bf16* O = Wt + (long long)z * 1048576;
    const int tx = t & 31, ty = t >> 5;
    const int n0 = bx * 32, k0 = by * 32;
#pragma unroll
    for (int i = 0; i < 4; i++)
      tile[ty + i * 8][tx] = W[(long long)(k0 + ty + i * 8) * 1024 + n0 + tx];
    __syncthreads();
#pragma unroll
    for (int i = 0; i < 4; i++)
      O[(long long)(n0 + ty + i * 8) * 1024 + k0 + tx] = (__bf16)tile[tx][ty + i * 8];
  } else if (bid < 6156) {
    const int i = (bid - 6144) * 256 + t;
    if (i < 3072) {
      const float* src = (i < 1024) ? bq : (i < 2048) ? bk : bv;
      bqkv[i] = src[i & 1023];
    }
  } else {
    // lsum(gr) at sb + (gr&127)*4096 + 2048 + (gr>>7)*4  (Sb batch-0 hole:
    // rows 0..127 only use cols [0,256); elems [1024,1280) are dead)
    const int gr = (bid - 6156) * 256 + t;  // 0..16383
    *(float*)(sb + (long long)(gr & 127) * 4096 + 2048 + (gr >> 7) * 4) = 0.0f;
  }
}

// ---------------------------------------------------------------- gemm2w: 128x256 tile, BK=32
// 8 waves (2M x 4N), per-wave 64x64 (acc[4][4]; ~60 VGPR -> 4 waves/SIMD).
// NBUF=3 (default): LDS 72 KiB (A 3x8 + B 3x16), 2 wgs/CU, 2-deep prefetch
//   issued BEFORE the MFMA block (target buf is not the one being read).
// NBUF=2: LDS 48 KiB (A 2x8 + B 2x16), 3 wgs/CU (all-resident for <=768 wgs).
//   1-deep prefetch: stage of tile kk+2 targets the CURRENT read buffer, so it
//   is issued AFTER the MFMA block (ds_reads provably retired: lgkmcnt precedes
//   MFMA; DMA write returns >=400cy after an issue point >=300cy past barrier1,
//   vs reads completing <=120cy past it). vmcnt(3) drains kk+1 (6->3, FIFO).
//   The 3rd co-resident wg supplies the TLP lost with the shallower pipeline.
// Swizzle ^(((row>>1)&3)<<4): free 2-way bank aliasing (262K conflicts, R8).
// OUT: 0 = bf16 C; 1 = f32 C;
//      2 = fused QKV z-routing (z<2 scalar bf16 C, z==2 V->vt_out[b][d][t]);
//      3 = S epilogue: causal mask + exp (no max-sub: |s|<~3 bounded), write
//          bf16 P, per-row sums atomicAdd into lsum (vt_out = Sb base);
//      4 = PV epilogue: scale by 1/lsum[row] (bias0 = lsum base as float*).
// SWZ: 0 = A-stripe (XCD q owns br in [16q,16q+16), br fastest; needs nbx=128)
//      4 = PV complementary-pair: 512 wgs; per-CU slot sum == 68 (exact).
//      5 = S-gemm causal: 576 wgs; z = XCD = batch; row-pair enumeration.
template <int OUT, int SWZ, int NBUF>
__global__ __launch_bounds__(512, 4) void gemm2w(
    const __bf16* __restrict__ A0, int lda, long long sAz,
    const __bf16* __restrict__ B0, int ldb, long long sBz,
    void* __restrict__ C0v, int ldc, long long sCz,
    const float* __restrict__ bias0, int sBiasZ,
    float scale_z0, int k_tiles_base, int k_tiles_per_br,
    __bf16* __restrict__ vt_out) {
  int br, bc, z;
  {
    const int lin = (blockIdx.z * gridDim.y + blockIdx.y) * gridDim.x + blockIdx.x;
    if (SWZ == 4) {
      // complementary-pair causal schedule (gridDim = 512,1,1)
      z = lin & 7;
      const int r = (lin >> 3) & 7;
      bc = (lin >> 6) & 3;
      const int half = lin >> 8;  // 0: long half (br 8..15), 1: short (7..0)
      br = half ? (7 - r) : (8 + r);
    } else if (SWZ == 5) {
      // packed causal 128x256 tiles (gridDim = 576,1,1)
      z = lin & 7;
      const int c = lin >> 3;  // 0..71
      int m = (int)((sqrtf((float)(4 * c + 1)) - 1.0f) * 0.5f);
      if (c < m * (m + 1)) m--;
      if (c >= (m + 1) * (m + 2)) m++;
      const int r = c - m * (m + 1);  // 0..2m+1
      if (r >= m + 1) { br = 2 * m + 1; bc = r - (m + 1); }
      else { br = 2 * m; bc = r; }
    } else {
      const int q = lin & 7, c = lin >> 3;
      br = q * 16 + (c & 15);
      const int rest = c >> 4;
      const int nby = gridDim.y;
      bc = rest % nby;
      z = rest / nby;
    }
  }
  const int kt = k_tiles_base + k_tiles_per_br * br;  // >= 2 (BK=32 units)

  // LDS: A bufs at buf*4096 (elems); B bufs at NBUF*4096 + buf*8192
  __shared__ __align__(16) __bf16 lds[NBUF * 12288];

  const int t = threadIdx.x, w = t >> 6, lane = t & 63;
  const int wm = w >> 2, wn = w & 3;
  const int ln15 = lane & 15, kq = lane >> 4;

  const __bf16* A = A0 + (long long)z * sAz + (long long)br * 128 * lda;
  const __bf16* B = B0 + (long long)z * sBz + (long long)bc * 256 * ldb;

  // staging src (dest linear o = t*16 bytes, inverse-swizzled; 64B rows;
  // swz touches bits 4-5, row = o>>6 unchanged -> lo = o ^ (((o>>7)&3)<<4))
  const __bf16* sA;
  const __bf16* sB[2];
  {
    int o = t * 16;
    int lo = o ^ (((o >> 7) & 3) << 4);
    sA = A + (long long)(lo >> 6) * lda + ((lo & 63) >> 1);
  }
#pragma unroll
  for (int i = 0; i < 2; i++) {
    int o = i * 8192 + t * 16;
    int lo = o ^ (((o >> 7) & 3) << 4);
    sB[i] = B + (long long)(lo >> 6) * ldb + ((lo & 63) >> 1);
  }

  auto stgA = [&](int buf, int g) {
    int kc = g < kt ? g : kt - 1;
    gload16(sA + kc * 32, lds + buf * 4096 + w * 512);
  };
  auto stgB = [&](int buf, int g) {
    int kc = g < kt ? g : kt - 1;
#pragma unroll
    for (int i = 0; i < 2; i++)
      gload16(sB[i] + kc * 32, lds + NBUF * 4096 + buf * 8192 + i * 4096 + w * 512);
  };

  f32x4 acc[4][4] = {};
  bf16x8 a[4], b[4];

  // prologue: tiles 0 and 1 (3 loads each); vmcnt(3) -> tile 0 resident
  stgA(0, 0); stgB(0, 0);
  stgA(1, 1); stgB(1, 1);
  asm volatile("s_waitcnt vmcnt(3)" ::: "memory");
  __builtin_amdgcn_s_barrier();
  FENCE;

  int cb = 0, db = 2;  // db used only for NBUF==3
  for (int kk = 0; kk < kt; kk++) {
    const char* Ab = (const char*)(lds + cb * 4096);
    const char* Bb = (const char*)(lds + NBUF * 4096 + cb * 8192);
#pragma unroll
    for (int mi = 0; mi < 4; mi++) {
      int row = wm * 64 + mi * 16 + ln15;
      int pb = (row * 64 + kq * 16) ^ (((row >> 1) & 3) << 4);
      a[mi] = *(const bf16x8*)(Ab + pb);
    }
#pragma unroll
    for (int ni = 0; ni < 4; ni++) {
      int row = wn * 64 + ni * 16 + ln15;
      int pb = (row * 64 + kq * 16) ^ (((row >> 1) & 3) << 4);
      b[ni] = *(const bf16x8*)(Bb + pb);
    }
    if (NBUF == 3) {
      stgA(db, kk + 2);
      stgB(db, kk + 2);
    }
    FENCE;
    __builtin_amdgcn_s_barrier();
    FENCE;
    __builtin_amdgcn_s_setprio(1);
#pragma unroll
    for (int mi = 0; mi < 4; mi++)
#pragma unroll
      for (int ni = 0; ni < 4; ni++)
        acc[mi][ni] = __builtin_amdgcn_mfma_f32_16x16x32_bf16(
            a[mi], b[ni], acc[mi][ni], 0, 0, 0);
    __builtin_amdgcn_s_setprio(0);
    if (NBUF == 2) {
      // post-MFMA: this buffer's ds_reads are retired; stage tile kk+2 here
      FENCE;
      stgA(cb, kk + 2);
      stgB(cb, kk + 2);
    }
    asm volatile("s_waitcnt vmcnt(3)" ::: "memory");
    __builtin_amdgcn_s_barrier();
    FENCE;
    cb = (cb == NBUF - 1) ? 0 : cb + 1;
    if (NBUF == 3) db = (db == 2) ? 0 : db + 1;
  }
  // drain clamped-dup prefetches before LDS reuse / exit (stale DMA safety)
  asm volatile("s_waitcnt vmcnt(0)" ::: "memory");

  if (OUT == 2 && z == 2) {
    // V: stage 128(t) x 256(d) tile into LDS as [d][t] (256B rows, XOR
    // ((d&7)<<4) -> 2-way), then coalesced 16B stores into vt_out[b][d][t].
    // (only instantiated with NBUF=3: 64 KB scratch fits the 72 KB LDS)
    __syncthreads();
    char* lb = (char*)lds;
#pragma unroll
    for (int mi = 0; mi < 4; mi++) {
#pragma unroll
      for (int ni = 0; ni < 4; ni++) {
        const int d = wn * 64 + ni * 16 + ln15;
        const int tl = wm * 64 + kq * 4 + mi * 16;
        const float bb = bias0[2048 + bc * 256 + d];
        ushort4_t p;
#pragma unroll
        for (int j = 0; j < 4; j++) {
          union { __bf16 h; unsigned short u; } cv;
          cv.h = (__bf16)(acc[mi][ni][j] + bb);
          p[j] = cv.u;
        }
        int byte = (d * 256 + tl * 2) ^ ((d & 7) << 4);
        *(ushort4_t*)(lb + byte) = p;
      }
    }
    __syncthreads();
    const int bz = br >> 4;
    const int t0 = (br & 15) * 128;
    __bf16* vbase = vt_out + (long long)bz * 2097152 +
                    (long long)(bc * 256) * 2048 + t0;
#pragma unroll
    for (int it = 0; it < 8; it++) {
      int idx = it * 512 + t;  // 16B units, 4096 total (256 d x 16)
      int d = idx >> 4, tc = idx & 15;
      int byte = (d * 256 + tc * 16) ^ ((d & 7) << 4);
      bf16x8 vv = *(const bf16x8*)(lb + byte);
      *(bf16x8*)(vbase + (long long)d * 2048 + tc * 8) = vv;
    }
  } else if (OUT == 3) {
    // S epilogue: causal mask + exp, write bf16 P, accumulate row sums.
    // lsum(gr) lives in the Sb batch-0 hole (see prep_k); vt_out = Sb base.
    char* lsb = (char*)vt_out;
    const int row0 = br * 128 + wm * 64 + kq * 4;
    const int col0 = bc * 256 + wn * 64 + ln15;
#pragma unroll
    for (int mi = 0; mi < 4; mi++) {
#pragma unroll
      for (int j = 0; j < 4; j++) {
        const int rr = row0 + mi * 16 + j;
        float psum = 0.0f;
#pragma unroll
        for (int ni = 0; ni < 4; ni++) {
          const int cc = col0 + ni * 16;
          float p = (cc <= rr) ? __expf(acc[mi][ni][j]) : 0.0f;
          __bf16 pb = (__bf16)p;
          ((__bf16*)C0v)[(long long)z * sCz + (long long)rr * ldc + cc] = pb;
          psum += (float)pb;  // sum the bf16-rounded values PV will consume
        }
        // reduce across the 16-lane col group (ln15 bits only)
#pragma unroll
        for (int o = 8; o >= 1; o >>= 1) psum += __shfl_xor(psum, o);
        if (ln15 == 0) {
          const int gr = z * 2048 + rr;
          atomicAdd((float*)(lsb + (long long)(gr & 127) * 4096 + 2048 +
                             (gr >> 7) * 4),
                    psum);
        }
      }
    }
  } else if (OUT == 4) {
    // PV epilogue: normalize by 1/lsum[row]; bias0 = lsum base (float*)
    const int row0 = br * 128 + wm * 64 + kq * 4;
    const int col0 = bc * 256 + wn * 64 + ln15;
#pragma unroll
    for (int mi = 0; mi < 4; mi++) {
#pragma unroll
      for (int j = 0; j < 4; j++) {
        const int rr = row0 + mi * 16 + j;
        const int gr = z * 2048 + rr;
        const float rl = 1.0f / bias0[(gr & 127) * 1024 + 512 + (gr >> 7)];
#pragma unroll
        for (int ni = 0; ni < 4; ni++) {
          const int cc = col0 + ni * 16;
          ((__bf16*)C0v)[(long long)z * sCz + (long long)rr * ldc + cc] =
              (__bf16)(acc[mi][ni][j] * rl);
        }
      }
    }
  } else {
    const int row0 = br * 128 + wm * 64 + kq * 4;
    const int col0 = bc * 256 + wn * 64 + ln15;
    const float scale = (z == 0) ? scale_z0 : 1.0f;
    const float* bias = bias0 ? (bias0 + (long long)z * sBiasZ) : nullptr;
#pragma unroll
    for (int mi = 0; mi < 4; mi++) {
#pragma unroll
      for (int ni = 0; ni < 4; ni++) {
        const int rr = row0 + mi * 16;
        const int cc = col0 + ni * 16;
        const float bb = bias ? bias[cc] : 0.0f;
#pragma unroll
        for (int j = 0; j < 4; j++) {
          float v = (acc[mi][ni][j] + bb) * scale;
          long long off = (long long)z * sCz + (long long)(rr + j) * ldc + cc;
          if (OUT == 1)
            ((float*)C0v)[off] = v;
          else
            ((__bf16*)C0v)[off] = (__bf16)v;
        }
      }
    }
  }
}

// ---------------------------------------------------------------- launch
extern "C" void kernel_launch(void* const* d_in, const int* in_sizes, int n_in,
                              void* d_out, int out_size, void* d_ws, size_t ws_size,
                              hipStream_t stream) {
  const float* y  = (const float*)d_in[0];
  const float* Wq = (const float*)d_in[1];
  const float* bq = (const float*)d_in[2];
  const float* Wk = (const float*)d_in[3];
  const float* bk = (const float*)d_in[4];
  const float* Wv = (const float*)d_in[5];
  const float* bv = (const float*)d_in[6];
  const float* Wo = (const float*)d_in[7];
  const float* bo = (const float*)d_in[8];

  char* ws = (char*)d_ws;
  __bf16* Xb   = (__bf16*)(ws + 0);            // 16384x1024 bf16 X   (32 MiB) [ctx after PV]
  __bf16* Wt   = (__bf16*)(ws + 33554432);     // 4 x [1024][1024] bf16 W^T (8 MiB)
  float*  bqkv = (float*)(ws + 41943040);      // 3x1024 fp32
  __bf16* Qb   = (__bf16*)(ws + 41955328);     // 8x2048x1024 Q       (32 MiB)
  __bf16* Kb   = (__bf16*)(ws + 75509760);     // 8x2048x1024 K       (32 MiB)
  __bf16* Vt   = (__bf16*)(ws + 109064192);    // 8 x [1024][2048] V^T (32 MiB)
  __bf16* Sb   = (__bf16*)(ws + 142618624);    // 8x2048x2048 S/P (ends at 209,727,488)
  __bf16* ctx  = (__bf16*)(ws + 0);            // PV output reuses Xb region

  if (ws_size < 209727488u) return;

  // fused prep: X->bf16, W transposes, bias pack, lsum zero (one launch)
  prep_k<<<6220, 256, 0, stream>>>(y, Wq, Wk, Wv, Wo, bq, bk, bv, Xb, Wt, bqkv,
                                   (char*)Sb);

  // Fused QKV projection: 128x256-tile, NBUF=3, 2 wgs/CU (unchanged config),
  // z-split (z0->Qb scaled, z1->Kb, z2->Vt via LDS transpose). A-stripe, z slowest.
  gemm2w<2, 0, 3><<<dim3(128, 4, 3), 512, 0, stream>>>(
      Xb, 1024, 0LL, Wt, 1024, 1048576LL,
      Qb, 1024, 16777216LL, bqkv, 1024, 0.03125f, 32, 0, Vt);

  // S = Q @ K^T with fused exp+mask+rowsum epilogue: NBUF=2 (48 KB LDS) ->
  // 3 wgs/CU -> all 576 wgs co-resident (no queued 3rd-wg tail per XCD).
  gemm2w<3, 5, 2><<<dim3(576, 1, 1), 512, 0, stream>>>(
      Qb, 1024, 2097152LL, Kb, 1024, 2097152LL,
      Sb, 2048, 4194304LL, nullptr, 0, 1.0f, 32, 0, Sb);

  // ctx = P @ V with 1/lsum normalization epilogue: complementary-pair
  // schedule (512 wgs, per-CU slot sum == 68, 2 wgs/CU, NBUF=3).
  gemm2w<4, 4, 3><<<dim3(512, 1, 1), 512, 0, stream>>>(
      Sb, 2048, 4194304LL, Vt, 2048, 2097152LL,
      ctx, 1024, 2097152LL, (const float*)Sb, 0, 1.0f, 4, 4, nullptr);

  // out = ctx @ Wo + bo (fp32 epilogue to d_out), gemm2w A-stripe, 2 wgs/CU
  gemm2w<1, 0, 3><<<dim3(128, 4, 1), 512, 0, stream>>>(
      ctx, 1024, 0LL, Wt + 3 * 1048576, 1024, 0LL,
      d_out, 1024, 0LL, bo, 0, 1.0f, 32, 0, nullptr);
}